// Round 3
// baseline (350.753 us; speedup 1.0000x reference)
//
#include <hip/hip_runtime.h>
#include <math.h>

#define NN 10000
#define EE 160000
#define EP 170000          // EE + NN self loops
#define NFEAT 256
#define NHID 128
#define NH 4
#define HF 512             // NH * NHID
#define NCLASS 40
#define FCOLS 1088         // 512 xh + 512 res + 8 attn + 56 pad

typedef __attribute__((ext_vector_type(8))) short bf8;     // 8 bf16 (4 VGPR) MFMA frag
typedef __attribute__((ext_vector_type(8))) unsigned short u16x8;
typedef __attribute__((ext_vector_type(4))) float f4;

__device__ __forceinline__ float leaky02(float x) { return x >= 0.0f ? x : 0.2f * x; }

__device__ __forceinline__ unsigned short f2bf(float f) {   // RNE
    unsigned u = __builtin_bit_cast(unsigned, f);
    unsigned r = (u + 0x7FFF + ((u >> 16) & 1)) >> 16;
    return (unsigned short)r;
}
__device__ __forceinline__ float bf2f(unsigned short h) {
    return __builtin_bit_cast(float, (unsigned)h << 16);
}

// ---------------- CSR build ----------------
__global__ __launch_bounds__(256)
void count_edges_k(const int* __restrict__ ei, int* __restrict__ cnt)
{
    int e = blockIdx.x * 256 + threadIdx.x;
    if (e >= EP) return;
    int d = (e < EE) ? ei[EE + e] : (e - EE);
    atomicAdd(&cnt[d], 1);
}

__global__ __launch_bounds__(256)
void scan_k(const int* __restrict__ cnt, int* __restrict__ row_ptr)
{
    __shared__ int sm[256];
    int t = threadIdx.x;
    int i0 = t * 40, i1 = min(i0 + 40, NN);
    int part = 0;
    for (int i = i0; i < i1; ++i) part += cnt[i];
    sm[t] = part;
    __syncthreads();
    for (int off = 1; off < 256; off <<= 1) {
        int v = (t >= off) ? sm[t - off] : 0;
        __syncthreads();
        sm[t] += v;
        __syncthreads();
    }
    int run = sm[t] - part;             // exclusive prefix
    for (int i = i0; i < i1; ++i) { row_ptr[i] = run; run += cnt[i]; }
    if (t == 255) row_ptr[NN] = run;
}

__global__ __launch_bounds__(256)
void fill_csr_k(const int* __restrict__ ei, const int* __restrict__ row_ptr,
                int* __restrict__ cursor, int* __restrict__ csr)
{
    int e = blockIdx.x * 256 + threadIdx.x;
    if (e >= EP) return;
    int s, d;
    if (e < EE) { s = ei[e]; d = ei[EE + e]; } else { s = e - EE; d = s; }
    int pos = row_ptr[d] + atomicAdd(&cursor[d], 1);
    csr[pos] = s;
}

// ---------------- hi/lo bf16 conversion of x + all weights (float4-vectorized) ----------------
#define C_X   2560000
#define C_EW  (C_X + 32768)
#define C_FW  (C_EW + 131072)      // gat_w (65536) + res_w (65536) -> fw rows 0..1023
#define C_DW  (C_FW + 5120)

__global__ __launch_bounds__(256)
void cvt_all_k(const float* __restrict__ x, const float* __restrict__ enc_w,
               const float* __restrict__ gat_w, const float* __restrict__ res_w,
               const float* __restrict__ dec_w,
               unsigned short* __restrict__ xhi, unsigned short* __restrict__ xlo,
               unsigned short* __restrict__ ewhi, unsigned short* __restrict__ ewlo,
               unsigned short* __restrict__ fwhi, unsigned short* __restrict__ fwlo,
               unsigned short* __restrict__ dwhi, unsigned short* __restrict__ dwlo)
{
    int i4 = blockIdx.x * 256 + threadIdx.x;
    int i = i4 * 4;
    if (i >= C_DW) return;
    const float* src; unsigned short *ph, *pl; int j;
    if (i < C_X)       { j = i;        src = x;     ph = xhi;  pl = xlo; }
    else if (i < C_EW) { j = i - C_X;  src = enc_w; ph = ewhi; pl = ewlo; }
    else if (i < C_FW) { j = i - C_EW;
                         if (j < 65536) src = gat_w; else { src = res_w; j -= 65536; }
                         ph = fwhi + (i - C_EW - j ? 65536 : 0); // adjust base
                         ph = fwhi; pl = fwlo; j = i - C_EW;     // fw is contiguous [gat;res]
                         src = nullptr; }
    else               { j = i - C_FW; src = dec_w; ph = dwhi; pl = dwlo; }

    float4 v;
    if (src) v = *(const float4*)(src + j);
    else {   // fused weight region: pick gat_w or res_w (regions 4-aligned, no straddle of 65536)
        v = (j < 65536) ? *(const float4*)(gat_w + j) : *(const float4*)(res_w + j - 65536);
    }
    float vv[4] = {v.x, v.y, v.z, v.w};
    unsigned short hs[4], ls[4];
#pragma unroll
    for (int k = 0; k < 4; ++k) {
        hs[k] = f2bf(vv[k]);
        ls[k] = f2bf(vv[k] - bf2f(hs[k]));
    }
    *(ushort4*)(ph + j) = make_ushort4(hs[0], hs[1], hs[2], hs[3]);
    *(ushort4*)(pl + j) = make_ushort4(ls[0], ls[1], ls[2], ls[3]);
}

// ---------------- fused attention weight rows: fw rows 1024..1031 (+ zero tail) ----------------
// As[h][k] = sum_c gat_w[h*128+c][k] * att_src[h][c]  (row 1024+h)
// Ad[h][k] = sum_c gat_w[h*128+c][k] * att_dst[h][c]  (row 1028+h)
__global__ __launch_bounds__(256)
void attw_k(const float* __restrict__ gat_w, const float* __restrict__ att_src,
            const float* __restrict__ att_dst,
            unsigned short* __restrict__ fwhi, unsigned short* __restrict__ fwlo)
{
    int t = threadIdx.x;
#pragma unroll
    for (int i = 0; i < 4; ++i) {
        int idx = t + i * 256;          // 0..1023
        int is_dst = idx >= 512;
        int hk = is_dst ? idx - 512 : idx;
        int h = hk >> 7, k = hk & 127;
        const float* att = is_dst ? att_dst : att_src;
        float s = 0.0f;
        for (int c = 0; c < 128; ++c)
            s = fmaf(gat_w[(size_t)(h * 128 + c) * 128 + k], att[h * 128 + c], s);
        unsigned short hi = f2bf(s);
        size_t o = (size_t)(1024 + (is_dst ? 4 : 0) + h) * 128 + k;
        fwhi[o] = hi;
        fwlo[o] = f2bf(s - bf2f(hi));
    }
    // zero pad rows 1032..1087
    for (int i = t; i < 56 * 128; i += 256) {
        fwhi[1032 * 128 + i] = 0;
        fwlo[1032 * 128 + i] = 0;
    }
}

// ---------------- bf16x3 MFMA GEMM: C = A @ W.T (+bias per mode) ----------------
// Block 64x64, 4 waves 2x2, wave 32x32 = 2x2 MFMA tiles, K in registers (no LDS).
// acc += Ah*Wh + Ah*Wl + Al*Wh.
// MODE 0: dec  -> outF[row*40+col]+dec_b, cols masked < 40
// MODE 1: enc  -> relu(v+enc_b) -> hi/lo bf16 to outH/outL, ld=128
// MODE 2: layer-> col<512: bf16 xh; 512..1023: fp32 res (+res_b); 1024..1031: a_src/a_dst
template<int MODE, int KSTEPS>
__global__ __launch_bounds__(256)
void gemm3_k(const unsigned short* __restrict__ Ahi, const unsigned short* __restrict__ Alo,
             const unsigned short* __restrict__ Bhi, const unsigned short* __restrict__ Blo,
             const float* __restrict__ bias,
             float* __restrict__ outF, unsigned short* __restrict__ outH,
             unsigned short* __restrict__ outL,
             float* __restrict__ a_src, float* __restrict__ a_dst, int M)
{
    constexpr int K = KSTEPS * 32;
    const int lane = threadIdx.x & 63, wv = threadIdx.x >> 6;
    const int wr = (wv >> 1) * 32, wc = (wv & 1) * 32;
    const int bm = blockIdx.x * 64, bn = blockIdx.y * 64;
    const int r16 = lane & 15, q8 = (lane >> 4) * 8;

    const size_t a0 = (size_t)min(bm + wr + r16,      M - 1) * K + q8;
    const size_t a1 = (size_t)min(bm + wr + 16 + r16, M - 1) * K + q8;
    const size_t b0 = (size_t)(bn + wc + r16)      * K + q8;
    const size_t b1 = (size_t)(bn + wc + 16 + r16) * K + q8;

    f4 acc[2][2];
#pragma unroll
    for (int i = 0; i < 2; ++i)
#pragma unroll
        for (int j = 0; j < 2; ++j) acc[i][j] = (f4){0.f, 0.f, 0.f, 0.f};

#pragma unroll
    for (int ks = 0; ks < KSTEPS; ++ks) {
        const int ko = ks * 32;
        bf8 A0h = *(const bf8*)(Ahi + a0 + ko);
        bf8 A1h = *(const bf8*)(Ahi + a1 + ko);
        bf8 A0l = *(const bf8*)(Alo + a0 + ko);
        bf8 A1l = *(const bf8*)(Alo + a1 + ko);
        bf8 B0h = *(const bf8*)(Bhi + b0 + ko);
        bf8 B1h = *(const bf8*)(Bhi + b1 + ko);
        bf8 B0l = *(const bf8*)(Blo + b0 + ko);
        bf8 B1l = *(const bf8*)(Blo + b1 + ko);

        acc[0][0] = __builtin_amdgcn_mfma_f32_16x16x32_bf16(A0h, B0h, acc[0][0], 0, 0, 0);
        acc[0][1] = __builtin_amdgcn_mfma_f32_16x16x32_bf16(A0h, B1h, acc[0][1], 0, 0, 0);
        acc[1][0] = __builtin_amdgcn_mfma_f32_16x16x32_bf16(A1h, B0h, acc[1][0], 0, 0, 0);
        acc[1][1] = __builtin_amdgcn_mfma_f32_16x16x32_bf16(A1h, B1h, acc[1][1], 0, 0, 0);
        acc[0][0] = __builtin_amdgcn_mfma_f32_16x16x32_bf16(A0h, B0l, acc[0][0], 0, 0, 0);
        acc[0][1] = __builtin_amdgcn_mfma_f32_16x16x32_bf16(A0h, B1l, acc[0][1], 0, 0, 0);
        acc[1][0] = __builtin_amdgcn_mfma_f32_16x16x32_bf16(A1h, B0l, acc[1][0], 0, 0, 0);
        acc[1][1] = __builtin_amdgcn_mfma_f32_16x16x32_bf16(A1h, B1l, acc[1][1], 0, 0, 0);
        acc[0][0] = __builtin_amdgcn_mfma_f32_16x16x32_bf16(A0l, B0h, acc[0][0], 0, 0, 0);
        acc[0][1] = __builtin_amdgcn_mfma_f32_16x16x32_bf16(A0l, B1h, acc[0][1], 0, 0, 0);
        acc[1][0] = __builtin_amdgcn_mfma_f32_16x16x32_bf16(A1l, B0h, acc[1][0], 0, 0, 0);
        acc[1][1] = __builtin_amdgcn_mfma_f32_16x16x32_bf16(A1l, B1h, acc[1][1], 0, 0, 0);
    }

    const int rbase = (lane >> 4) * 4;
#pragma unroll
    for (int i = 0; i < 2; ++i)
#pragma unroll
        for (int j = 0; j < 2; ++j)
#pragma unroll
            for (int r = 0; r < 4; ++r) {
                int row = bm + wr + i * 16 + rbase + r;
                int col = bn + wc + j * 16 + r16;
                if (row >= M) continue;
                float v = acc[i][j][r];
                if (MODE == 1) {
                    v = fmaxf(v + bias[col], 0.0f);
                    unsigned short h = f2bf(v);
                    outH[(size_t)row * 128 + col] = h;
                    outL[(size_t)row * 128 + col] = f2bf(v - bf2f(h));
                } else if (MODE == 2) {
                    if (col < 512) {
                        outH[(size_t)row * 512 + col] = f2bf(v);
                    } else if (col < 1024) {
                        outF[(size_t)row * 512 + col - 512] = v + bias[col - 512];
                    } else if (col < 1032) {
                        int h = col - 1024;
                        if (h < 4) a_src[row * 4 + h] = v;
                        else       a_dst[row * 4 + h - 4] = v;
                    }
                } else {
                    if (col < NCLASS)
                        outF[(size_t)row * NCLASS + col] = v + bias[col];
                }
            }
}

// ---------------- per-edge unnormalized softmax weights (head-major) + per-node sums ------
__global__ __launch_bounds__(256)
void alpha_k(const int* __restrict__ row_ptr, const int* __restrict__ csr,
             const float* __restrict__ a_src, const float* __restrict__ a_dst,
             float* __restrict__ t, float* __restrict__ ssum)
{
    int wave = threadIdx.x >> 6, lane = threadIdx.x & 63;
    int d = blockIdx.x * 4 + wave;
    if (d >= NN) return;
    int beg = row_ptr[d], end = row_ptr[d + 1];
    float4 ad = *(const float4*)(a_dst + d * 4);
    float s0 = 0.f, s1 = 0.f, s2 = 0.f, s3 = 0.f;
    for (int e = beg + lane; e < end; e += 64) {
        int s = csr[e];
        float4 as = *(const float4*)(a_src + s * 4);
        float t0 = expf(leaky02(as.x + ad.x));
        float t1 = expf(leaky02(as.y + ad.y));
        float t2 = expf(leaky02(as.z + ad.z));
        float t3 = expf(leaky02(as.w + ad.w));
        t[0 * EP + e] = t0;
        t[1 * EP + e] = t1;
        t[2 * EP + e] = t2;
        t[3 * EP + e] = t3;
        s0 += t0; s1 += t1; s2 += t2; s3 += t3;
    }
#pragma unroll
    for (int off = 32; off >= 1; off >>= 1) {
        s0 += __shfl_xor(s0, off);
        s1 += __shfl_xor(s1, off);
        s2 += __shfl_xor(s2, off);
        s3 += __shfl_xor(s3, off);
    }
    if (lane == 0) *(float4*)(ssum + d * 4) = make_float4(s0, s1, s2, s3);
}

// ---------------- gather + residual + ELU + head-mean -> X (hi/lo bf16) ----------------
// Unrolled x4 for memory ILP; softmax normalization folded into final scale.
__global__ __launch_bounds__(256)
void agg_k(const int* __restrict__ row_ptr, const int* __restrict__ csr,
           const float* __restrict__ t, const float* __restrict__ ssum,
           const unsigned short* __restrict__ xh_b, const float* __restrict__ res,
           const float* __restrict__ gat_b,
           unsigned short* __restrict__ Xhi, unsigned short* __restrict__ Xlo)
{
    int wave = threadIdx.x >> 6, lane = threadIdx.x & 63;
    int d = blockIdx.x * 4 + wave;
    if (d >= NN) return;
    int beg = row_ptr[d], end = row_ptr[d + 1];
    int hl = lane >> 4;                       // head owned by this lane's cols
    int cb = lane * 8;                        // 8 bf16 cols = 16 B per lane
    const float* th = t + (size_t)hl * EP;

    float acc[8];
#pragma unroll
    for (int k = 0; k < 8; ++k) acc[k] = 0.0f;

    int e = beg;
    for (; e + 4 <= end; e += 4) {
        int s0v = csr[e + 0], s1v = csr[e + 1], s2v = csr[e + 2], s3v = csr[e + 3];
        float w0 = th[e + 0], w1 = th[e + 1], w2 = th[e + 2], w3 = th[e + 3];
        u16x8 v0 = *(const u16x8*)(xh_b + (size_t)s0v * HF + cb);
        u16x8 v1 = *(const u16x8*)(xh_b + (size_t)s1v * HF + cb);
        u16x8 v2 = *(const u16x8*)(xh_b + (size_t)s2v * HF + cb);
        u16x8 v3 = *(const u16x8*)(xh_b + (size_t)s3v * HF + cb);
#pragma unroll
        for (int k = 0; k < 8; ++k) acc[k] = fmaf(w0, bf2f(v0[k]), acc[k]);
#pragma unroll
        for (int k = 0; k < 8; ++k) acc[k] = fmaf(w1, bf2f(v1[k]), acc[k]);
#pragma unroll
        for (int k = 0; k < 8; ++k) acc[k] = fmaf(w2, bf2f(v2[k]), acc[k]);
#pragma unroll
        for (int k = 0; k < 8; ++k) acc[k] = fmaf(w3, bf2f(v3[k]), acc[k]);
    }
    for (; e < end; ++e) {
        int s = csr[e];
        float w = th[e];
        u16x8 v = *(const u16x8*)(xh_b + (size_t)s * HF + cb);
#pragma unroll
        for (int k = 0; k < 8; ++k) acc[k] = fmaf(w, bf2f(v[k]), acc[k]);
    }

    float inv = 1.0f / ssum[d * 4 + hl];
    const float* rr = res + (size_t)d * HF + cb;
    const float* gb = gat_b + cb;
    float u[8];
#pragma unroll
    for (int k = 0; k < 8; ++k) {
        float v = fmaf(acc[k], inv, gb[k] + rr[k]);
        u[k] = (v > 0.0f) ? v : expm1f(v);
    }
    float z0 = (u[0] + u[1] + u[2] + u[3]) * 0.25f;
    float z1 = (u[4] + u[5] + u[6] + u[7]) * 0.25f;
    unsigned short h0 = f2bf(z0), h1 = f2bf(z1);
    unsigned short l0 = f2bf(z0 - bf2f(h0)), l1 = f2bf(z1 - bf2f(h1));
    size_t idx = (size_t)d * NHID + lane * 2;
    *(unsigned*)(Xhi + idx) = ((unsigned)h1 << 16) | h0;
    *(unsigned*)(Xlo + idx) = ((unsigned)l1 << 16) | l0;
}

// ---------------- launcher ----------------
extern "C" void kernel_launch(void* const* d_in, const int* in_sizes, int n_in,
                              void* d_out, int out_size, void* d_ws, size_t ws_size,
                              hipStream_t stream)
{
    const float* x       = (const float*)d_in[0];
    const int*   ei      = (const int*)d_in[1];
    const float* enc_w   = (const float*)d_in[2];
    const float* enc_b   = (const float*)d_in[3];
    const float* res_w   = (const float*)d_in[4];
    const float* res_b   = (const float*)d_in[5];
    const float* gat_w   = (const float*)d_in[6];
    const float* att_src = (const float*)d_in[7];
    const float* att_dst = (const float*)d_in[8];
    const float* gat_b   = (const float*)d_in[9];
    const float* dec_w   = (const float*)d_in[10];
    const float* dec_b   = (const float*)d_in[11];
    float* out = (float*)d_out;

    char* p = (char*)d_ws;
    auto alloc = [&](size_t bytes) -> void* {
        void* r = (void*)p;
        p += (bytes + 255) & ~(size_t)255;
        return r;
    };
    float* res    = (float*)alloc(5120000 * 4);            // [N,512] fp32
    float* t      = (float*)alloc(4 * EP * 4);             // [4][EP] head-major
    float* a_src  = (float*)alloc(40000 * 4);
    float* a_dst  = (float*)alloc(40000 * 4);
    float* ssum   = (float*)alloc(40000 * 4);
    unsigned short* xh_b = (unsigned short*)alloc(5120000 * 2);     // [N,512] bf16
    unsigned short* Xhi  = (unsigned short*)alloc(1280000 * 2);     // [N,128] bf16
    unsigned short* Xlo  = (unsigned short*)alloc(1280000 * 2);
    unsigned short* xhi  = (unsigned short*)alloc(2560000 * 2);     // x hi/lo [N,256]
    unsigned short* xlo  = (unsigned short*)alloc(2560000 * 2);
    unsigned short* ewhi = (unsigned short*)alloc(32768 * 2);       // enc_w [128,256]
    unsigned short* ewlo = (unsigned short*)alloc(32768 * 2);
    unsigned short* fwhi = (unsigned short*)alloc(FCOLS * 128 * 2); // [1088,128]
    unsigned short* fwlo = (unsigned short*)alloc(FCOLS * 128 * 2);
    int* row_ptr = (int*)alloc(10004 * 4);
    int* csr     = (int*)alloc(170000 * 4);
    // ---- zero zone (single memset): padded dec W + cnt + cursor ----
    char* zbase = p;
    unsigned short* dwhi = (unsigned short*)alloc(8192 * 2);        // [64,128] padded
    unsigned short* dwlo = (unsigned short*)alloc(8192 * 2);
    int* cnt    = (int*)alloc(10000 * 4);
    int* cursor = (int*)alloc(10000 * 4);
    size_t zbytes = (size_t)(p - zbase);

    hipMemsetAsync(zbase, 0, zbytes, stream);

    // CSR build (graph static across both layers)
    int eb = (EP + 255) / 256;
    count_edges_k<<<eb, 256, 0, stream>>>(ei, cnt);
    scan_k<<<1, 256, 0, stream>>>(cnt, row_ptr);
    fill_csr_k<<<eb, 256, 0, stream>>>(ei, row_ptr, cursor, csr);

    // hi/lo conversions (x + all weights), float4-vectorized
    cvt_all_k<<<(C_DW / 4 + 255) / 256, 256, 0, stream>>>(
        x, enc_w, gat_w, res_w, dec_w,
        xhi, xlo, ewhi, ewlo, fwhi, fwlo, dwhi, dwlo);
    // fused attention weight rows (fw rows 1024..1031 + zero tail)
    attw_k<<<1, 256, 0, stream>>>(gat_w, att_src, att_dst, fwhi, fwlo);

    // encoder: X = relu(x @ enc_w.T + enc_b) -> hi/lo bf16
    gemm3_k<1, 8><<<dim3(157, 2), 256, 0, stream>>>(
        xhi, xlo, ewhi, ewlo, enc_b, nullptr, Xhi, Xlo, nullptr, nullptr, NN);

    for (int layer = 0; layer < 2; ++layer) {
        // fused [xh | res | a_src a_dst] = X @ [gat_w; res_w; As; Ad].T
        gemm3_k<2, 4><<<dim3(157, 17), 256, 0, stream>>>(
            Xhi, Xlo, fwhi, fwlo, res_b, res, xh_b, nullptr, a_src, a_dst, NN);
        alpha_k<<<2500, 256, 0, stream>>>(row_ptr, csr, a_src, a_dst, t, ssum);
        agg_k<<<2500, 256, 0, stream>>>(row_ptr, csr, t, ssum, xh_b, res, gat_b, Xhi, Xlo);
    }

    // decoder: out = X @ dec_w.T + dec_b
    gemm3_k<0, 4><<<dim3(157, 1), 256, 0, stream>>>(
        Xhi, Xlo, dwhi, dwlo, dec_b, out, nullptr, nullptr, nullptr, nullptr, NN);
}